// Round 6
// baseline (490.772 us; speedup 1.0000x reference)
//
#include <hip/hip_runtime.h>
#include <hip/hip_bf16.h>
#include <math.h>

#define F_IN 256
#define F_OUT 64
#define NEG_SLOPE 0.2f
#define SHIFT 7
#define NPB 128            // nodes per bucket
#define MAXK 1024          // max buckets (N <= 131072, matches 17-bit j pack)
#define CAP 4608           // LDS staging records/bucket (mean 4096, +8 sigma)
#define OVF 4              // per-thread overflow regs (+1024 records headroom)
#define GRID_B 256         // blocks for count/bin (ranges must match)

// ---------------------------------------------------------------------------
// GEMM: h16 = bf16(x @ W), a_src = h@att_src, a_dst = h@att_dst (fp32).
// (unchanged)
// ---------------------------------------------------------------------------
__global__ __launch_bounds__(256) void gemm_kernel(
    const float* __restrict__ x, const float* __restrict__ W,
    const float* __restrict__ att_src, const float* __restrict__ att_dst,
    __hip_bfloat16* __restrict__ h16, float* __restrict__ a_src,
    float* __restrict__ a_dst, int N)
{
    __shared__ float sX[64][65];      // [k within chunk][row], padded
    __shared__ float sPa[4][64];
    __shared__ float sPd[4][64];

    const int t = threadIdx.x;
    const int lane = t & 63;
    const int w = t >> 6;
    const int rowBase = blockIdx.x * 64;
    const int row = rowBase + lane;
    const int c0 = __builtin_amdgcn_readfirstlane(w * 16);  // uniform col base

    float acc[16];
#pragma unroll
    for (int c = 0; c < 16; c++) acc[c] = 0.f;

    const int kq = t & 15;   // k quarter: float4 at k = kq*4
    const int rr = t >> 4;   // row sub-index 0..15

    for (int kc = 0; kc < F_IN / 64; kc++) {
#pragma unroll
        for (int p = 0; p < 4; p++) {
            int r = rr + p * 16;
            float4 v = make_float4(0.f, 0.f, 0.f, 0.f);
            if (rowBase + r < N)
                v = *(const float4*)&x[(size_t)(rowBase + r) * F_IN + kc * 64 + kq * 4];
            sX[kq * 4 + 0][r] = v.x;
            sX[kq * 4 + 1][r] = v.y;
            sX[kq * 4 + 2][r] = v.z;
            sX[kq * 4 + 3][r] = v.w;
        }
        __syncthreads();

        const float* Wc = W + (size_t)(kc * 64) * F_OUT + c0;
#pragma unroll 4
        for (int kk = 0; kk < 64; kk++) {
            float xv = sX[kk][lane];
            const float* wr = Wc + (size_t)kk * F_OUT;   // uniform address
#pragma unroll
            for (int c = 0; c < 16; c++)
                acc[c] = fmaf(xv, wr[c], acc[c]);
        }
        __syncthreads();
    }

    float asp = 0.f, adp = 0.f;
#pragma unroll
    for (int c = 0; c < 16; c++) {
        asp = fmaf(acc[c], att_src[c0 + c], asp);
        adp = fmaf(acc[c], att_dst[c0 + c], adp);
    }
    sPa[w][lane] = asp;
    sPd[w][lane] = adp;

    if (row < N) {
        __hip_bfloat16 tmp[16];
#pragma unroll
        for (int c = 0; c < 16; c++) tmp[c] = __float2bfloat16(acc[c]);
        int4* dst = (int4*)(h16 + (size_t)row * F_OUT + c0);
        dst[0] = ((int4*)tmp)[0];
        dst[1] = ((int4*)tmp)[1];
    }

    __syncthreads();
    if (w == 0 && row < N) {
        a_src[row] = sPa[0][lane] + sPa[1][lane] + sPa[2][lane] + sPa[3][lane];
        a_dst[row] = sPd[0][lane] + sPd[1][lane] + sPd[2][lane] + sPd[3][lane];
    }
}

// ---------------------------------------------------------------------------
// Count: per-block LDS bucket histogram -> pbh[block][K] (no global atomics).
// ---------------------------------------------------------------------------
__global__ __launch_bounds__(1024) void bucket_count_kernel(
    const int* __restrict__ dst, int* __restrict__ pbh, int E, int K, int R)
{
    __shared__ int s[MAXK];
    const int t = threadIdx.x;
    for (int b = t; b < K; b += 1024) s[b] = 0;
    __syncthreads();
    const int start = blockIdx.x * R;
    const int end = min(E, start + R);
    for (int e = start + t * 4; e < end; e += 4096) {
        if (e + 3 < end) {
            int4 d = *(const int4*)&dst[e];
            atomicAdd(&s[d.x >> SHIFT], 1);
            atomicAdd(&s[d.y >> SHIFT], 1);
            atomicAdd(&s[d.z >> SHIFT], 1);
            atomicAdd(&s[d.w >> SHIFT], 1);
        } else {
            for (int q = e; q < end; q++) atomicAdd(&s[dst[q] >> SHIFT], 1);
        }
    }
    __syncthreads();
    int* row = pbh + (size_t)blockIdx.x * K;
    for (int b = t; b < K; b += 1024) row[b] = s[b];
}

// ---------------------------------------------------------------------------
// Scan: bucket totals (sum pbh over blocks), exclusive scan -> bbase,
// then per-(block,bucket) deterministic chunk bases cbase[block][K].
// All global accesses coalesced across threads.
// ---------------------------------------------------------------------------
__global__ __launch_bounds__(1024) void bucket_scan_kernel(
    const int* __restrict__ pbh, int* __restrict__ bbase,
    int* __restrict__ cbase, int K, int E, int NBLK)
{
    __shared__ int s[1024];
    const int t = threadIdx.x;
    int tot = 0;
    if (t < K)
        for (int b = 0; b < NBLK; b++) tot += pbh[(size_t)b * K + t];
    s[t] = (t < K) ? tot : 0;
    __syncthreads();
    for (int off = 1; off < 1024; off <<= 1) {
        int v = (t >= off) ? s[t - off] : 0;
        __syncthreads();
        s[t] += v;
        __syncthreads();
    }
    if (t < K) {
        int base = s[t] - tot;        // exclusive
        bbase[t] = base;
        int run = base;
        for (int b = 0; b < NBLK; b++) {
            cbase[(size_t)b * K + t] = run;
            run += pbh[(size_t)b * K + t];
        }
    }
    if (t == 0) bbase[K] = E;
}

// ---------------------------------------------------------------------------
// Bin: single sweep. LDS cursors preloaded with this block's deterministic
// chunk bases; per edge: one LDS atomic + one 4-B write into the block's
// ~50 KB window. Record = j | local_i << 17 (p recomputed later).
// ---------------------------------------------------------------------------
__global__ __launch_bounds__(1024) void bin_kernel(
    const int* __restrict__ ei, const int* __restrict__ cbase,
    int* __restrict__ rec, int E, int K, int R)
{
    __shared__ int cb[MAXK];
    const int t = threadIdx.x;
    const int start = blockIdx.x * R;
    const int end = min(E, start + R);
    const int* crow = cbase + (size_t)blockIdx.x * K;
    for (int b = t; b < K; b += 1024) cb[b] = crow[b];
    __syncthreads();

    for (int e = start + t * 4; e < end; e += 4096) {
        if (e + 3 < end) {
            int4 jj = *(const int4*)&ei[e];
            int4 ii = *(const int4*)&ei[E + e];
            int p0 = atomicAdd(&cb[ii.x >> SHIFT], 1);
            int p1 = atomicAdd(&cb[ii.y >> SHIFT], 1);
            int p2 = atomicAdd(&cb[ii.z >> SHIFT], 1);
            int p3 = atomicAdd(&cb[ii.w >> SHIFT], 1);
            rec[p0] = jj.x | ((ii.x & (NPB - 1)) << 17);
            rec[p1] = jj.y | ((ii.y & (NPB - 1)) << 17);
            rec[p2] = jj.z | ((ii.z & (NPB - 1)) << 17);
            rec[p3] = jj.w | ((ii.w & (NPB - 1)) << 17);
        } else {
            for (int q = e; q < end; q++) {
                int j = ei[q], i = ei[E + q];
                int pos = atomicAdd(&cb[i >> SHIFT], 1);
                rec[pos] = j | ((i & (NPB - 1)) << 17);
            }
        }
    }
}

// ---------------------------------------------------------------------------
// Sort: one block per bucket; stage 4-B records in LDS (+overflow regs),
// count 128 local degrees, block-scan, in-place ordered write-back + row_ptr.
// ---------------------------------------------------------------------------
__global__ __launch_bounds__(256) void sort_kernel(
    int* __restrict__ rec, const int* __restrict__ bbase,
    int* __restrict__ row_ptr, int N, int E, int K)
{
    __shared__ int stage[CAP];
    __shared__ int deg[NPB];
    __shared__ int sval[NPB];
    __shared__ int base[NPB];
    __shared__ int cnt[NPB];
    const int t = threadIdx.x;
    const int b = blockIdx.x;
    const int s = bbase[b], e = bbase[b + 1];
    const int tot = e - s;
    const int nodeBase = b << SHIFT;
    const int nodes = min(NPB, N - nodeBase);

    if (t < NPB) deg[t] = 0;
    __syncthreads();

    int ovf[OVF];
    for (int r = t; r < tot; r += 256) {
        int m = rec[s + r];
        if (r < CAP) stage[r] = m;
        else { int k = (r - CAP) >> 8; if (k < OVF) ovf[k] = m; }
        atomicAdd(&deg[(m >> 17) & (NPB - 1)], 1);
    }
    __syncthreads();

    if (t < NPB) sval[t] = deg[t];
    __syncthreads();
    for (int off = 1; off < NPB; off <<= 1) {
        int v = (t < NPB && t >= off) ? sval[t - off] : 0;
        __syncthreads();
        if (t < NPB) sval[t] += v;
        __syncthreads();
    }
    if (t < NPB) {
        base[t] = sval[t] - deg[t];              // exclusive
        cnt[t] = 0;
        if (t < nodes) row_ptr[nodeBase + t] = s + base[t];
    }
    if (b == K - 1 && t == 0) row_ptr[N] = E;
    __syncthreads();

    for (int r = t; r < tot; r += 256) {
        int m = (r < CAP) ? stage[r] : ovf[(r - CAP) >> 8];
        int li = (m >> 17) & (NPB - 1);
        int rk = atomicAdd(&cnt[li], 1);
        rec[s + base[li] + rk] = m;              // 16-KB window, L2-combined
    }
}

// ---------------------------------------------------------------------------
// Node aggregation: one wave/node, lane=feature; p recomputed from a_src/
// a_dst (L2-resident) — 8-deep batches keep meta + a_src + h16 in flight.
// ---------------------------------------------------------------------------
__global__ __launch_bounds__(256) void node_kernel(
    const __hip_bfloat16* __restrict__ h16, const float* __restrict__ a_src,
    const float* __restrict__ a_dst, const int* __restrict__ row_ptr,
    const int* __restrict__ rec, const float* __restrict__ bias,
    float* __restrict__ out, int N)
{
    int w = threadIdx.x >> 6;
    int lane = threadIdx.x & 63;
    int i = blockIdx.x * 4 + w;
    if (i >= N) return;

    int s = row_ptr[i];
    int e = row_ptr[i + 1];

    const float adst_i = a_dst[i];
    float vs = a_src[i] + adst_i;
    vs = (vs > 0.f) ? vs : NEG_SLOPE * vs;
    float pself = __expf(vs);
    float den = pself;
    float acc = pself * __bfloat162float(h16[(size_t)i * F_OUT + lane]);

    int k = s;
    for (; k + 8 <= e; k += 8) {
        int m[8];
#pragma unroll
        for (int u = 0; u < 8; u++) m[u] = rec[k + u] & 0x1FFFF;
        asm volatile("" ::: "memory");   // keep meta loads batched
        float as[8], g[8];
#pragma unroll
        for (int u = 0; u < 8; u++) {
            as[u] = a_src[m[u]];
            g[u] = __bfloat162float(h16[(size_t)m[u] * F_OUT + lane]);
        }
        asm volatile("" ::: "memory");   // keep 16 loads in flight
#pragma unroll
        for (int u = 0; u < 8; u++) {
            float v = as[u] + adst_i;
            v = (v > 0.f) ? v : NEG_SLOPE * v;
            float p = __expf(v);
            den += p;
            acc = fmaf(p, g[u], acc);
        }
    }
    for (; k < e; k++) {
        int j = rec[k] & 0x1FFFF;
        float v = a_src[j] + adst_i;
        v = (v > 0.f) ? v : NEG_SLOPE * v;
        float p = __expf(v);
        den += p;
        acc = fmaf(p, __bfloat162float(h16[(size_t)j * F_OUT + lane]), acc);
    }

    out[(size_t)i * F_OUT + lane] = acc / (den + 1e-16f) + bias[lane];
}

// ---------------------------------------------------------------------------
extern "C" void kernel_launch(void* const* d_in, const int* in_sizes, int n_in,
                              void* d_out, int out_size, void* d_ws, size_t ws_size,
                              hipStream_t stream)
{
    const float* x      = (const float*)d_in[0];
    const int*   ei     = (const int*)d_in[1];
    const float* W      = (const float*)d_in[2];
    const float* att_sr = (const float*)d_in[3];
    const float* att_ds = (const float*)d_in[4];
    const float* bias   = (const float*)d_in[5];
    float* out = (float*)d_out;

    const int N = in_sizes[0] / F_IN;
    const int E = in_sizes[1] / 2;
    const int K = (N + NPB - 1) >> SHIFT;   // 782 for N=100000
    const int R = (((E + GRID_B - 1) / GRID_B) + 3) & ~3;   // per-block range, x4

    char* ws = (char*)d_ws;
    size_t off = 0;
    auto alloc = [&](size_t bytes) -> void* {
        void* p = ws + off;
        off = (off + bytes + 255) & ~(size_t)255;
        return p;
    };
    __hip_bfloat16* h16 = (__hip_bfloat16*)alloc((size_t)N * F_OUT * 2);
    float* a_src   = (float*)alloc((size_t)N * 4);
    float* a_dst   = (float*)alloc((size_t)N * 4);
    int*   pbh     = (int*)alloc((size_t)GRID_B * K * 4);
    int*   cbase   = (int*)alloc((size_t)GRID_B * K * 4);
    int*   bbase   = (int*)alloc((size_t)(K + 1) * 4);
    int*   row_ptr = (int*)alloc((size_t)(N + 1) * 4);
    int*   rec     = (int*)alloc((size_t)E * 4);
    (void)ws_size; (void)n_in; (void)out_size;

    gemm_kernel<<<(N + 63) / 64, 256, 0, stream>>>(x, W, att_sr, att_ds, h16, a_src, a_dst, N);
    bucket_count_kernel<<<GRID_B, 1024, 0, stream>>>(ei + E, pbh, E, K, R);
    bucket_scan_kernel<<<1, 1024, 0, stream>>>(pbh, bbase, cbase, K, E, GRID_B);
    bin_kernel<<<GRID_B, 1024, 0, stream>>>(ei, cbase, rec, E, K, R);
    sort_kernel<<<K, 256, 0, stream>>>(rec, bbase, row_ptr, N, E, K);
    node_kernel<<<(N + 3) / 4, 256, 0, stream>>>(h16, a_src, a_dst, row_ptr, rec, bias, out, N);
}

// Round 7
// 386.578 us; speedup vs baseline: 1.2695x; 1.2695x over previous
//
#include <hip/hip_runtime.h>
#include <hip/hip_bf16.h>
#include <math.h>

#define F_IN 256
#define F_OUT 64
#define NEG_SLOPE 0.2f
#define SHIFT 7
#define NPB 128            // nodes per bucket
#define MAXK 1024          // max buckets (N <= 131072, matches 17-bit j pack)
#define CAP 4608           // LDS staging records/bucket (mean 4096, +8 sigma)
#define OVF 4              // per-thread overflow regs (+1024 records headroom)
#define GRID_B 256         // blocks for count/bin (ranges must match)

__device__ __forceinline__ float bf2f(__hip_bfloat16 v) {
    return __bfloat162float(v);
}

// ---------------------------------------------------------------------------
// GEMM: h16 = bf16(x @ W), a_src = h@att_src, a_dst = h@att_dst (fp32).
// (unchanged)
// ---------------------------------------------------------------------------
__global__ __launch_bounds__(256) void gemm_kernel(
    const float* __restrict__ x, const float* __restrict__ W,
    const float* __restrict__ att_src, const float* __restrict__ att_dst,
    __hip_bfloat16* __restrict__ h16, float* __restrict__ a_src,
    float* __restrict__ a_dst, int N)
{
    __shared__ float sX[64][65];      // [k within chunk][row], padded
    __shared__ float sPa[4][64];
    __shared__ float sPd[4][64];

    const int t = threadIdx.x;
    const int lane = t & 63;
    const int w = t >> 6;
    const int rowBase = blockIdx.x * 64;
    const int row = rowBase + lane;
    const int c0 = __builtin_amdgcn_readfirstlane(w * 16);  // uniform col base

    float acc[16];
#pragma unroll
    for (int c = 0; c < 16; c++) acc[c] = 0.f;

    const int kq = t & 15;   // k quarter: float4 at k = kq*4
    const int rr = t >> 4;   // row sub-index 0..15

    for (int kc = 0; kc < F_IN / 64; kc++) {
#pragma unroll
        for (int p = 0; p < 4; p++) {
            int r = rr + p * 16;
            float4 v = make_float4(0.f, 0.f, 0.f, 0.f);
            if (rowBase + r < N)
                v = *(const float4*)&x[(size_t)(rowBase + r) * F_IN + kc * 64 + kq * 4];
            sX[kq * 4 + 0][r] = v.x;
            sX[kq * 4 + 1][r] = v.y;
            sX[kq * 4 + 2][r] = v.z;
            sX[kq * 4 + 3][r] = v.w;
        }
        __syncthreads();

        const float* Wc = W + (size_t)(kc * 64) * F_OUT + c0;
#pragma unroll 4
        for (int kk = 0; kk < 64; kk++) {
            float xv = sX[kk][lane];
            const float* wr = Wc + (size_t)kk * F_OUT;   // uniform address
#pragma unroll
            for (int c = 0; c < 16; c++)
                acc[c] = fmaf(xv, wr[c], acc[c]);
        }
        __syncthreads();
    }

    float asp = 0.f, adp = 0.f;
#pragma unroll
    for (int c = 0; c < 16; c++) {
        asp = fmaf(acc[c], att_src[c0 + c], asp);
        adp = fmaf(acc[c], att_dst[c0 + c], adp);
    }
    sPa[w][lane] = asp;
    sPd[w][lane] = adp;

    if (row < N) {
        __hip_bfloat16 tmp[16];
#pragma unroll
        for (int c = 0; c < 16; c++) tmp[c] = __float2bfloat16(acc[c]);
        int4* dst = (int4*)(h16 + (size_t)row * F_OUT + c0);
        dst[0] = ((int4*)tmp)[0];
        dst[1] = ((int4*)tmp)[1];
    }

    __syncthreads();
    if (w == 0 && row < N) {
        a_src[row] = sPa[0][lane] + sPa[1][lane] + sPa[2][lane] + sPa[3][lane];
        a_dst[row] = sPd[0][lane] + sPd[1][lane] + sPd[2][lane] + sPd[3][lane];
    }
}

// ---------------------------------------------------------------------------
// Count: per-block LDS bucket histogram -> pbh[block][K] (no global atomics).
// ---------------------------------------------------------------------------
__global__ __launch_bounds__(1024) void bucket_count_kernel(
    const int* __restrict__ dst, int* __restrict__ pbh, int E, int K, int R)
{
    __shared__ int s[MAXK];
    const int t = threadIdx.x;
    for (int b = t; b < K; b += 1024) s[b] = 0;
    __syncthreads();
    const int start = blockIdx.x * R;
    const int end = min(E, start + R);
    for (int e = start + t * 4; e < end; e += 4096) {
        if (e + 3 < end) {
            int4 d = *(const int4*)&dst[e];
            atomicAdd(&s[d.x >> SHIFT], 1);
            atomicAdd(&s[d.y >> SHIFT], 1);
            atomicAdd(&s[d.z >> SHIFT], 1);
            atomicAdd(&s[d.w >> SHIFT], 1);
        } else {
            for (int q = e; q < end; q++) atomicAdd(&s[dst[q] >> SHIFT], 1);
        }
    }
    __syncthreads();
    int* row = pbh + (size_t)blockIdx.x * K;
    for (int b = t; b < K; b += 1024) row[b] = s[b];
}

// ---------------------------------------------------------------------------
// Column scan: one wave per bucket k. 64 lanes scan the 256 per-block counts
// in 4 chunks (wave shfl-scan + carry) -> cbase[block][k] (exclusive, base 0)
// and per-bucket total btot[k]. Fully parallel across 782 blocks.
// ---------------------------------------------------------------------------
__global__ __launch_bounds__(64) void colscan_kernel(
    const int* __restrict__ pbh, int* __restrict__ cbase,
    int* __restrict__ btot, int K, int NBLK)
{
    const int k = blockIdx.x;
    const int lane = threadIdx.x;
    // prefetch all chunks (NBLK <= 256 -> 4 chunks)
    int v[4];
#pragma unroll
    for (int c = 0; c < 4; c++) {
        int b = c * 64 + lane;
        v[c] = (b < NBLK) ? pbh[(size_t)b * K + k] : 0;
    }
    int carry = 0;
#pragma unroll
    for (int c = 0; c < 4; c++) {
        int orig = v[c];
        int s = v[c];
#pragma unroll
        for (int off = 1; off < 64; off <<= 1) {
            int u = __shfl_up(s, off, 64);
            if (lane >= off) s += u;
        }
        int b = c * 64 + lane;
        if (b < NBLK) cbase[(size_t)b * K + k] = carry + s - orig;  // exclusive
        carry += __shfl(s, 63, 64);
    }
    if (lane == 0) btot[k] = carry;
}

// ---------------------------------------------------------------------------
// Bucket base scan: exclusive scan of btot -> bbase (K <= 1024, one block).
// ---------------------------------------------------------------------------
__global__ __launch_bounds__(1024) void bbase_scan_kernel(
    const int* __restrict__ btot, int* __restrict__ bbase, int K, int E)
{
    __shared__ int s[1024];
    const int t = threadIdx.x;
    int v = (t < K) ? btot[t] : 0;
    s[t] = v;
    __syncthreads();
    for (int off = 1; off < 1024; off <<= 1) {
        int u = (t >= off) ? s[t - off] : 0;
        __syncthreads();
        s[t] += u;
        __syncthreads();
    }
    if (t < K) bbase[t] = s[t] - v;       // exclusive
    if (t == 0) bbase[K] = E;
}

// ---------------------------------------------------------------------------
// Bin: single sweep. LDS cursors = bbase[b] + this block's chunk base;
// per edge: one LDS atomic + one 4-B write into the block's ~50 KB window.
// Record = j | local_i << 17 (p recomputed in node_kernel).
// ---------------------------------------------------------------------------
__global__ __launch_bounds__(1024) void bin_kernel(
    const int* __restrict__ ei, const int* __restrict__ cbase,
    const int* __restrict__ bbase, int* __restrict__ rec, int E, int K, int R)
{
    __shared__ int cb[MAXK];
    const int t = threadIdx.x;
    const int start = blockIdx.x * R;
    const int end = min(E, start + R);
    const int* crow = cbase + (size_t)blockIdx.x * K;
    for (int b = t; b < K; b += 1024) cb[b] = bbase[b] + crow[b];
    __syncthreads();

    for (int e = start + t * 4; e < end; e += 4096) {
        if (e + 3 < end) {
            int4 jj = *(const int4*)&ei[e];
            int4 ii = *(const int4*)&ei[E + e];
            int p0 = atomicAdd(&cb[ii.x >> SHIFT], 1);
            int p1 = atomicAdd(&cb[ii.y >> SHIFT], 1);
            int p2 = atomicAdd(&cb[ii.z >> SHIFT], 1);
            int p3 = atomicAdd(&cb[ii.w >> SHIFT], 1);
            rec[p0] = jj.x | ((ii.x & (NPB - 1)) << 17);
            rec[p1] = jj.y | ((ii.y & (NPB - 1)) << 17);
            rec[p2] = jj.z | ((ii.z & (NPB - 1)) << 17);
            rec[p3] = jj.w | ((ii.w & (NPB - 1)) << 17);
        } else {
            for (int q = e; q < end; q++) {
                int j = ei[q], i = ei[E + q];
                int pos = atomicAdd(&cb[i >> SHIFT], 1);
                rec[pos] = j | ((i & (NPB - 1)) << 17);
            }
        }
    }
}

// ---------------------------------------------------------------------------
// Sort: one block per bucket; stage 4-B records in LDS (+overflow regs),
// count 128 local degrees, block-scan, in-place ordered write-back + row_ptr.
// ---------------------------------------------------------------------------
__global__ __launch_bounds__(256) void sort_kernel(
    int* __restrict__ rec, const int* __restrict__ bbase,
    int* __restrict__ row_ptr, int N, int E, int K)
{
    __shared__ int stage[CAP];
    __shared__ int deg[NPB];
    __shared__ int sval[NPB];
    __shared__ int base[NPB];
    __shared__ int cnt[NPB];
    const int t = threadIdx.x;
    const int b = blockIdx.x;
    const int s = bbase[b], e = bbase[b + 1];
    const int tot = e - s;
    const int nodeBase = b << SHIFT;
    const int nodes = min(NPB, N - nodeBase);

    if (t < NPB) deg[t] = 0;
    __syncthreads();

    int ovf[OVF];
    for (int r = t; r < tot; r += 256) {
        int m = rec[s + r];
        if (r < CAP) stage[r] = m;
        else { int k = (r - CAP) >> 8; if (k < OVF) ovf[k] = m; }
        atomicAdd(&deg[(m >> 17) & (NPB - 1)], 1);
    }
    __syncthreads();

    if (t < NPB) sval[t] = deg[t];
    __syncthreads();
    for (int off = 1; off < NPB; off <<= 1) {
        int v = (t < NPB && t >= off) ? sval[t - off] : 0;
        __syncthreads();
        if (t < NPB) sval[t] += v;
        __syncthreads();
    }
    if (t < NPB) {
        base[t] = sval[t] - deg[t];              // exclusive
        cnt[t] = 0;
        if (t < nodes) row_ptr[nodeBase + t] = s + base[t];
    }
    if (b == K - 1 && t == 0) row_ptr[N] = E;
    __syncthreads();

    for (int r = t; r < tot; r += 256) {
        int m = (r < CAP) ? stage[r] : ovf[(r - CAP) >> 8];
        int li = (m >> 17) & (NPB - 1);
        int rk = atomicAdd(&cnt[li], 1);
        rec[s + base[li] + rk] = m;              // 16-KB window, L2-combined
    }
}

// ---------------------------------------------------------------------------
// Node aggregation: one wave/node, lane=EDGE for the softmax math (one exp
// per 64 edges instead of 64), lane=feature for the h accumulate.
// j/p broadcast via __shfl (readlane, scalar pipe). den reduced once/node.
// ---------------------------------------------------------------------------
__global__ __launch_bounds__(256) void node_kernel(
    const __hip_bfloat16* __restrict__ h16, const float* __restrict__ a_src,
    const float* __restrict__ a_dst, const int* __restrict__ row_ptr,
    const int* __restrict__ rec, const float* __restrict__ bias,
    float* __restrict__ out, int N)
{
    const int w = threadIdx.x >> 6;
    const int lane = threadIdx.x & 63;
    const int i = blockIdx.x * 4 + w;
    if (i >= N) return;

    const int s = row_ptr[i];
    const int e = row_ptr[i + 1];

    const float adst_i = a_dst[i];
    float vs = a_src[i] + adst_i;
    vs = fmaxf(vs, NEG_SLOPE * vs);              // LeakyReLU(0.2)
    const float pself = __expf(vs);
    float denl = (lane == 0) ? pself : 0.f;      // per-lane den partials
    float acc = pself * bf2f(h16[(size_t)i * F_OUT + lane]);

    for (int k = s; k < e; k += 64) {
        const int cnt = min(64, e - k);
        int r = (lane < cnt) ? rec[k + lane] : 0;      // coalesced
        int j = r & 0x1FFFF;
        float v = a_src[j] + adst_i;                   // scattered gather
        v = fmaxf(v, NEG_SLOPE * v);
        float p = __expf(v);                           // ONE exp / 64 edges
        if (lane >= cnt) p = 0.f;
        denl += p;

        int u = 0;
        for (; u + 8 <= cnt; u += 8) {
            int ju[8]; float pu[8], g[8];
#pragma unroll
            for (int c = 0; c < 8; c++) {
                ju[c] = __shfl(j, u + c, 64);
                pu[c] = __shfl(p, u + c, 64);
            }
#pragma unroll
            for (int c = 0; c < 8; c++)
                g[c] = bf2f(h16[(size_t)ju[c] * F_OUT + lane]);
            asm volatile("" ::: "memory");   // keep 8 gathers in flight
#pragma unroll
            for (int c = 0; c < 8; c++)
                acc = fmaf(pu[c], g[c], acc);
        }
        for (; u < cnt; u++) {
            int jc = __shfl(j, u, 64);
            float pc = __shfl(p, u, 64);
            acc = fmaf(pc, bf2f(h16[(size_t)jc * F_OUT + lane]), acc);
        }
    }

    float den = denl;
#pragma unroll
    for (int o = 32; o > 0; o >>= 1) den += __shfl_xor(den, o, 64);

    out[(size_t)i * F_OUT + lane] = acc / (den + 1e-16f) + bias[lane];
}

// ---------------------------------------------------------------------------
extern "C" void kernel_launch(void* const* d_in, const int* in_sizes, int n_in,
                              void* d_out, int out_size, void* d_ws, size_t ws_size,
                              hipStream_t stream)
{
    const float* x      = (const float*)d_in[0];
    const int*   ei     = (const int*)d_in[1];
    const float* W      = (const float*)d_in[2];
    const float* att_sr = (const float*)d_in[3];
    const float* att_ds = (const float*)d_in[4];
    const float* bias   = (const float*)d_in[5];
    float* out = (float*)d_out;

    const int N = in_sizes[0] / F_IN;
    const int E = in_sizes[1] / 2;
    const int K = (N + NPB - 1) >> SHIFT;   // 782 for N=100000
    const int R = (((E + GRID_B - 1) / GRID_B) + 3) & ~3;   // per-block range, x4

    char* ws = (char*)d_ws;
    size_t off = 0;
    auto alloc = [&](size_t bytes) -> void* {
        void* p = ws + off;
        off = (off + bytes + 255) & ~(size_t)255;
        return p;
    };
    __hip_bfloat16* h16 = (__hip_bfloat16*)alloc((size_t)N * F_OUT * 2);
    float* a_src   = (float*)alloc((size_t)N * 4);
    float* a_dst   = (float*)alloc((size_t)N * 4);
    int*   pbh     = (int*)alloc((size_t)GRID_B * K * 4);
    int*   cbase   = (int*)alloc((size_t)GRID_B * K * 4);
    int*   btot    = (int*)alloc((size_t)K * 4);
    int*   bbase   = (int*)alloc((size_t)(K + 1) * 4);
    int*   row_ptr = (int*)alloc((size_t)(N + 1) * 4);
    int*   rec     = (int*)alloc((size_t)E * 4);
    (void)ws_size; (void)n_in; (void)out_size;

    gemm_kernel<<<(N + 63) / 64, 256, 0, stream>>>(x, W, att_sr, att_ds, h16, a_src, a_dst, N);
    bucket_count_kernel<<<GRID_B, 1024, 0, stream>>>(ei + E, pbh, E, K, R);
    colscan_kernel<<<K, 64, 0, stream>>>(pbh, cbase, btot, K, GRID_B);
    bbase_scan_kernel<<<1, 1024, 0, stream>>>(btot, bbase, K, E);
    bin_kernel<<<GRID_B, 1024, 0, stream>>>(ei, cbase, bbase, rec, E, K, R);
    sort_kernel<<<K, 256, 0, stream>>>(rec, bbase, row_ptr, N, E, K);
    node_kernel<<<(N + 3) / 4, 256, 0, stream>>>(h16, a_src, a_dst, row_ptr, rec, bias, out, N);
}